// Round 1
// 375.112 us; speedup vs baseline: 1.0952x; 1.0952x over previous
//
#include <hip/hip_runtime.h>
#include <hip/hip_bf16.h>
#include <math.h>

#define BB 4
#define LL 4096
#define DM 256
#define DI 512
#define DS 16
#define NOUTK 128
#define LN_EPS 1e-5f
#define NC 128
#define CLEN (LL/NC)
#define BL (BB*LL)
#define LDB 640

typedef __attribute__((ext_vector_type(8))) short short8;
typedef __attribute__((ext_vector_type(4))) float f32x4;

__device__ __forceinline__ ushort f2bf(float f) {
    union { float f; unsigned u; } v; v.f = f;
    unsigned r = (v.u + 0x7FFF + ((v.u >> 16) & 1)) >> 16;
    return (ushort)r;
}
__device__ __forceinline__ float bf2f(ushort u) {
    union { unsigned u; float f; } v; v.u = ((unsigned)u) << 16;
    return v.f;
}

// ---------------- weight prep ----------------------------------------------
__global__ __launch_bounds__(256) void cast_bf16_kernel(
    const float* __restrict__ src, ushort* __restrict__ dst, int n)
{
    int i = blockIdx.x * 256 + threadIdx.x;
    if (i < n) dst[i] = f2bf(src[i]);
}

// combined xproj weight: rows [0,512) = dtw @ xpw[:16]  (fused dtproj)
//                        rows [512,544) = xpw rows 16..47 (B, C)
//                        rows [544,640) = 0
__global__ __launch_bounds__(256) void build_comb_kernel(
    const float* __restrict__ xpw, const float* __restrict__ dtw,
    ushort* __restrict__ dst)
{
    int i = blockIdx.x * 256 + threadIdx.x;      // over 2*640*512
    int l = i / (640 * 512);
    int rem = i - l * 640 * 512;
    int row = rem >> 9, k = rem & 511;
    const float* xp = xpw + l * 48 * 512;
    const float* dw = dtw + l * 512 * 16;
    float v;
    if (row < 512) {
        v = 0.f;
        #pragma unroll
        for (int r = 0; r < 16; ++r)
            v = fmaf(dw[row * 16 + r], xp[r * 512 + k], v);
    } else if (row < 544) {
        v = xp[(row - 512 + 16) * 512 + k];
    } else v = 0.f;
    dst[i] = f2bf(v);
}

// ---------------- encoder --------------------------------------------------
__global__ __launch_bounds__(256) void enc_kernel(
    const float* __restrict__ x, const float* __restrict__ w,
    const float* __restrict__ b, float* __restrict__ h,
    ushort* __restrict__ hbf)
{
    __shared__ float sw[256 * 33];
    __shared__ float sx[4][32];
    int tid = threadIdx.x;
    for (int i = tid; i < 256 * 8; i += 256) {
        float4 v = ((const float4*)w)[i];
        int r = i >> 3, c = (i & 7) * 4;
        sw[r * 33 + c + 0] = v.x; sw[r * 33 + c + 1] = v.y;
        sw[r * 33 + c + 2] = v.z; sw[r * 33 + c + 3] = v.w;
    }
    int row0 = blockIdx.x * 4;
    if (tid < 32) {
        for (int rr = 0; rr < 4; ++rr)
            sx[rr][tid] = x[(size_t)(row0 + rr) * 32 + tid];
    }
    __syncthreads();
    float bb = b[tid];
    #pragma unroll
    for (int rr = 0; rr < 4; ++rr) {
        float acc = bb;
        #pragma unroll
        for (int k = 0; k < 32; ++k)
            acc = fmaf(sx[rr][k], sw[tid * 33 + k], acc);
        size_t o = (size_t)(row0 + rr) * DM + tid;
        h[o] = acc;
        hbf[o] = f2bf(acc);
    }
}

// ---------------- bf16 MFMA GEMM: C = epi(A @ W^T) -------------------------
// EPI: 0 none; 1 combined-xproj:
//        cols<512:   dt_bf[row*ldcbf+col]  = bf16(softplus(v + bias[col]))
//        512<=c<544: bc  [row*ldc + c-512] = v   (f32 B/C block)
// Pipelined: double-buffered LDS (2x32KB), prefetch tile t+1 before
// computing tile t; one __syncthreads per k-step (implicit vmcnt(0) drain
// is the counted wait). XCD-chunked block swizzle keeps the col-blocks of
// one A row-panel on a single XCD L2.
template<int EPI, bool F32OUT, bool RESID, bool BF16OUT>
__global__ __launch_bounds__(256) void mfma_gemm(
    const ushort* __restrict__ A, int lda,
    const ushort* __restrict__ W,
    const float* __restrict__ bias,
    float* __restrict__ C, int ldc,
    ushort* __restrict__ Cbf, int ldcbf,
    int K)
{
    __shared__ ushort As[2][128 * 64];
    __shared__ ushort Ws[2][128 * 64];
    const int tid = threadIdx.x;

    // XCD-aware bijective swizzle (nwg % 8 == 0 for all our launches)
    int nwg = gridDim.x * gridDim.y;
    int wlin = blockIdx.y * gridDim.x + blockIdx.x;
    int gx = blockIdx.x, gy = blockIdx.y;
    if ((nwg & 7) == 0) {
        int q = nwg >> 3;
        int s = (wlin & 7) * q + (wlin >> 3);
        gx = s % gridDim.x;
        gy = s / gridDim.x;
    }
    const int bm = gy * 128;
    const int bn = gx * 128;
    const int wid = tid >> 6, lane = tid & 63;
    const int wrow = (wid >> 1) * 64, wcol = (wid & 1) * 64;
    const int sr = tid >> 3;
    const int sc = tid & 7;

    f32x4 acc[4][4];
    #pragma unroll
    for (int mi = 0; mi < 4; ++mi)
        #pragma unroll
        for (int ni = 0; ni < 4; ++ni)
            acc[mi][ni] = (f32x4){0.f, 0.f, 0.f, 0.f};

#define STAGE(b, k0) do {                                                     \
    _Pragma("unroll")                                                         \
    for (int it = 0; it < 4; ++it) {                                          \
        int r = it * 32 + sr;                                                 \
        int csrc = sc ^ (r & 7);                                              \
        __builtin_amdgcn_global_load_lds(                                     \
            (const __attribute__((address_space(1))) unsigned int*)           \
                (A + (size_t)(bm + r) * lda + (k0) + csrc * 8),               \
            (__attribute__((address_space(3))) unsigned int*)                 \
                (&As[b][r * 64 + sc * 8]), 16, 0, 0);                         \
    }                                                                         \
    _Pragma("unroll")                                                         \
    for (int it = 0; it < 4; ++it) {                                          \
        int r = it * 32 + sr;                                                 \
        int csrc = sc ^ (r & 7);                                              \
        __builtin_amdgcn_global_load_lds(                                     \
            (const __attribute__((address_space(1))) unsigned int*)           \
                (W + (size_t)(bn + r) * K + (k0) + csrc * 8),                 \
            (__attribute__((address_space(3))) unsigned int*)                 \
                (&Ws[b][r * 64 + sc * 8]), 16, 0, 0);                         \
    }                                                                         \
} while (0)

#define COMPUTE(b) do {                                                       \
    _Pragma("unroll")                                                         \
    for (int kk = 0; kk < 2; ++kk) {                                          \
        short8 af[4], bfr[4];                                                 \
        _Pragma("unroll")                                                     \
        for (int mi = 0; mi < 4; ++mi) {                                      \
            int r = wrow + mi * 16 + (lane & 15);                             \
            int c = (lane >> 4) + kk * 4;                                     \
            af[mi] = *(const short8*)(&As[b][r * 64 + ((c ^ (r & 7)) << 3)]); \
        }                                                                     \
        _Pragma("unroll")                                                     \
        for (int ni = 0; ni < 4; ++ni) {                                      \
            int r = wcol + ni * 16 + (lane & 15);                             \
            int c = (lane >> 4) + kk * 4;                                     \
            bfr[ni] = *(const short8*)(&Ws[b][r * 64 + ((c ^ (r & 7)) << 3)]);\
        }                                                                     \
        _Pragma("unroll")                                                     \
        for (int mi = 0; mi < 4; ++mi)                                        \
            _Pragma("unroll")                                                 \
            for (int ni = 0; ni < 4; ++ni)                                    \
                acc[mi][ni] = __builtin_amdgcn_mfma_f32_16x16x32_bf16(        \
                    af[mi], bfr[ni], acc[mi][ni], 0, 0, 0);                   \
    }                                                                         \
} while (0)

    const int nk = K >> 6;          // 4 (K=256) or 8 (K=512) — always even
    STAGE(0, 0);
    for (int t = 0; t < nk; t += 2) {
        __syncthreads();                        // buf0 of this pair ready
        if (t + 1 < nk) STAGE(1, (t + 1) << 6); // prefetch overlaps compute
        COMPUTE(0);
        __syncthreads();                        // buf1 ready
        if (t + 2 < nk) STAGE(0, (t + 2) << 6);
        COMPUTE(1);
    }
#undef STAGE
#undef COMPUTE

    #pragma unroll
    for (int mi = 0; mi < 4; ++mi)
        #pragma unroll
        for (int ni = 0; ni < 4; ++ni) {
            int col = bn + wcol + ni * 16 + (lane & 15);
            #pragma unroll
            for (int r = 0; r < 4; ++r) {
                int row = bm + wrow + mi * 16 + (lane >> 4) * 4 + r;
                float v = acc[mi][ni][r];
                if (EPI == 1) {
                    if (col < 512) {
                        float u = v + bias[col];
                        float sp = fmaxf(u, 0.f) + __logf(1.f + __expf(-fabsf(u)));
                        Cbf[(size_t)row * ldcbf + col] = f2bf(sp);
                    } else if (col < 544) {
                        C[(size_t)row * ldc + (col - 512)] = v;
                    }
                } else {
                    if (F32OUT) {
                        float* cp = C + (size_t)row * ldc + col;
                        float vv = v;
                        if (RESID) vv += *cp;
                        *cp = vv;
                        if (BF16OUT) Cbf[(size_t)row * ldcbf + col] = f2bf(vv);
                    } else if (BF16OUT) {
                        Cbf[(size_t)row * ldcbf + col] = f2bf(v);
                    }
                }
            }
        }
}

// ---------------- causal conv (width 4) + bias + silu, bf16 in/out ---------
__global__ __launch_bounds__(256) void conv_silu_kernel(
    const ushort* __restrict__ xz, const float* __restrict__ cw,
    const float* __restrict__ cb, ushort* __restrict__ xi)
{
    int idx = blockIdx.x * 256 + threadIdx.x;   // over BL*128
    int d4 = (idx & 127) * 4;
    int bt = idx >> 7;
    int t = bt & (LL - 1);
    const ushort* base = xz + (size_t)bt * 1024 + d4;
    float acc[4];
    float4 w[4];
    #pragma unroll
    for (int j = 0; j < 4; ++j) {
        acc[j] = cb[d4 + j];
        w[j] = *(const float4*)(cw + (d4 + j) * 4);
    }
    #pragma unroll
    for (int k = 0; k < 4; ++k) {
        int back = 3 - k;
        if (t >= back) {
            ushort4 v = *(const ushort4*)(base - back * 1024);
            float wk0 = (k==0)?w[0].x:(k==1)?w[0].y:(k==2)?w[0].z:w[0].w;
            float wk1 = (k==0)?w[1].x:(k==1)?w[1].y:(k==2)?w[1].z:w[1].w;
            float wk2 = (k==0)?w[2].x:(k==1)?w[2].y:(k==2)?w[2].z:w[2].w;
            float wk3 = (k==0)?w[3].x:(k==1)?w[3].y:(k==2)?w[3].z:w[3].w;
            acc[0] = fmaf(bf2f(v.x), wk0, acc[0]);
            acc[1] = fmaf(bf2f(v.y), wk1, acc[1]);
            acc[2] = fmaf(bf2f(v.z), wk2, acc[2]);
            acc[3] = fmaf(bf2f(v.w), wk3, acc[3]);
        }
    }
    ushort4 o;
    float s0 = acc[0] / (1.f + __expf(-acc[0]));
    float s1 = acc[1] / (1.f + __expf(-acc[1]));
    float s2 = acc[2] / (1.f + __expf(-acc[2]));
    float s3 = acc[3] / (1.f + __expf(-acc[3]));
    o.x = f2bf(s0); o.y = f2bf(s1); o.z = f2bf(s2); o.w = f2bf(s3);
    *(ushort4*)(xi + (size_t)bt * 512 + d4) = o;
}

// ---------------- chunked selective scan -----------------------------------
// dt (softplus applied) is bf16 at dtb[row*512 + d]; B/C are f32 at
// bc[row*32 + {0..15 | 16..31}].
__global__ __launch_bounds__(256) void scan_phase1(
    const ushort* __restrict__ xi, const ushort* __restrict__ dtb,
    const float* __restrict__ bc,
    const float* __restrict__ alog,
    float* __restrict__ cA, float* __restrict__ cH)
{
    int d = blockIdx.z * 256 + threadIdx.x;
    int b = blockIdx.y, c = blockIdx.x;
    float Av[16];
    bool fast = true;
    #pragma unroll
    for (int s = 0; s < 16; ++s) {
        Av[s] = -__expf(alog[d * 16 + s]);
        fast = fast && (fabsf(Av[s] + (float)(s + 1)) < 1e-3f * (s + 1));
    }
    float h[16], P[16];
    #pragma unroll
    for (int s = 0; s < 16; ++s) { h[s] = 0.f; P[s] = 1.f; }
    int t0 = c * CLEN;
    if (fast) {
        float Pe = 1.f;
        for (int t = t0; t < t0 + CLEN; ++t) {
            size_t row = (size_t)b * LL + t;
            float dt = bf2f(dtb[row * 512 + d]);
            float x = bf2f(xi[row * 512 + d]);
            float dtx = dt * x;
            const float* bp = bc + row * 32;
            float e1 = __expf(-dt);
            float e2=e1*e1, e3=e2*e1, e4=e2*e2, e5=e3*e2, e6=e3*e3, e7=e4*e3, e8=e4*e4;
            float e9=e5*e4, e10=e5*e5, e11=e6*e5, e12=e6*e6, e13=e7*e6, e14=e7*e7, e15=e8*e7, e16=e8*e8;
            float pw[16] = {e1,e2,e3,e4,e5,e6,e7,e8,e9,e10,e11,e12,e13,e14,e15,e16};
            #pragma unroll
            for (int s = 0; s < 16; ++s)
                h[s] = fmaf(pw[s], h[s], dtx * bp[s]);
            Pe *= e1;
        }
        float p1=Pe, p2=p1*p1, p3=p2*p1, p4=p2*p2, p5=p3*p2, p6=p3*p3, p7=p4*p3, p8=p4*p4;
        float p9=p5*p4, p10=p5*p5, p11=p6*p5, p12=p6*p6, p13=p7*p6, p14=p7*p7, p15=p8*p7, p16=p8*p8;
        float pp[16] = {p1,p2,p3,p4,p5,p6,p7,p8,p9,p10,p11,p12,p13,p14,p15,p16};
        #pragma unroll
        for (int s = 0; s < 16; ++s) P[s] = pp[s];
    } else {
        for (int t = t0; t < t0 + CLEN; ++t) {
            size_t row = (size_t)b * LL + t;
            float dt = bf2f(dtb[row * 512 + d]);
            float x = bf2f(xi[row * 512 + d]);
            float dtx = dt * x;
            const float* bp = bc + row * 32;
            #pragma unroll
            for (int s = 0; s < 16; ++s) {
                float dA = __expf(dt * Av[s]);
                h[s] = fmaf(dA, h[s], dtx * bp[s]);
                P[s] *= dA;
            }
        }
    }
    size_t base = (((size_t)b * DI + d) * NC + c) * 16;
    #pragma unroll
    for (int q = 0; q < 4; ++q) {
        *(float4*)(cA + base + q*4) = *(float4*)&P[q*4];
        *(float4*)(cH + base + q*4) = *(float4*)&h[q*4];
    }
}

__global__ __launch_bounds__(256) void scan_phase2(
    const float* __restrict__ cA, float* __restrict__ cH)
{
    int idx = blockIdx.x * 256 + threadIdx.x;  // (b*DI+d)*16 + s
    int s = idx & 15;
    int bd = idx >> 4;
    size_t base = (size_t)bd * NC * 16 + s;
    float init = 0.f;
    for (int c = 0; c < NC; ++c) {
        size_t o = base + (size_t)c * 16;
        float a = cA[o], hh = cH[o];
        cH[o] = init;
        init = fmaf(a, init, hh);
    }
}

__global__ __launch_bounds__(256) void scan_phase3(
    const ushort* __restrict__ xz,   // bf16, ld 1024; res at cols 512..1023
    ushort* __restrict__ xi,
    const ushort* __restrict__ dtb,
    const float* __restrict__ bc,
    const float* __restrict__ alog,
    const float* __restrict__ Dp,
    const float* __restrict__ cH,
    int c0)
{
    int d = blockIdx.z * 256 + threadIdx.x;
    int b = blockIdx.y;
    int c = blockIdx.x + c0;
    float Av[16];
    bool fast = true;
    #pragma unroll
    for (int s = 0; s < 16; ++s) {
        Av[s] = -__expf(alog[d * 16 + s]);
        fast = fast && (fabsf(Av[s] + (float)(s + 1)) < 1e-3f * (s + 1));
    }
    float h[16];
    size_t cbase = (((size_t)b * DI + d) * NC + c) * 16;
    #pragma unroll
    for (int q = 0; q < 4; ++q)
        *(float4*)&h[q*4] = *(const float4*)(cH + cbase + q*4);
    float Dd = Dp[d];
    int t0 = c * CLEN;
    if (fast) {
        for (int t = t0; t < t0 + CLEN; ++t) {
            size_t row = (size_t)b * LL + t;
            float dt = bf2f(dtb[row * 512 + d]);
            float x = bf2f(xi[row * 512 + d]);
            float dtx = dt * x;
            const float* bp = bc + row * 32;
            const float* cp = bc + row * 32 + 16;
            float e1 = __expf(-dt);
            float e2=e1*e1, e3=e2*e1, e4=e2*e2, e5=e3*e2, e6=e3*e3, e7=e4*e3, e8=e4*e4;
            float e9=e5*e4, e10=e5*e5, e11=e6*e5, e12=e6*e6, e13=e7*e6, e14=e7*e7, e15=e8*e7, e16=e8*e8;
            float pw[16] = {e1,e2,e3,e4,e5,e6,e7,e8,e9,e10,e11,e12,e13,e14,e15,e16};
            float y = 0.f;
            #pragma unroll
            for (int s = 0; s < 16; ++s) {
                h[s] = fmaf(pw[s], h[s], dtx * bp[s]);
                y = fmaf(h[s], cp[s], y);
            }
            float res = bf2f(xz[row * 1024 + 512 + d]);
            float g = (y + x * Dd) * (res / (1.f + __expf(-res)));
            xi[row * 512 + d] = f2bf(g);
        }
    } else {
        for (int t = t0; t < t0 + CLEN; ++t) {
            size_t row = (size_t)b * LL + t;
            float dt = bf2f(dtb[row * 512 + d]);
            float x = bf2f(xi[row * 512 + d]);
            float dtx = dt * x;
            const float* bp = bc + row * 32;
            const float* cp = bc + row * 32 + 16;
            float y = 0.f;
            #pragma unroll
            for (int s = 0; s < 16; ++s) {
                float dA = __expf(dt * Av[s]);
                h[s] = fmaf(dA, h[s], dtx * bp[s]);
                y = fmaf(h[s], cp[s], y);
            }
            float res = bf2f(xz[row * 1024 + 512 + d]);
            float g = (y + x * Dd) * (res / (1.f + __expf(-res)));
            xi[row * 512 + d] = f2bf(g);
        }
    }
}

// ---------------- last-row out_proj (layer 2) ------------------------------
__global__ __launch_bounds__(256) void out_proj_last_kernel(
    const ushort* __restrict__ xi, const float* __restrict__ W,
    float* __restrict__ h)
{
    int b = blockIdx.x, n = threadIdx.x;
    __shared__ float sy[DI];
    const ushort* yrow = xi + ((size_t)b * LL + (LL - 1)) * DI;
    for (int k = threadIdx.x; k < DI; k += 256) sy[k] = bf2f(yrow[k]);
    __syncthreads();
    const float* wr = W + (size_t)n * DI;
    float acc = 0.f;
    for (int k = 0; k < DI; k += 4) {
        float4 wv = *(const float4*)(wr + k);
        acc = fmaf(sy[k+0], wv.x, acc);
        acc = fmaf(sy[k+1], wv.y, acc);
        acc = fmaf(sy[k+2], wv.z, acc);
        acc = fmaf(sy[k+3], wv.w, acc);
    }
    h[((size_t)b * LL + (LL - 1)) * DM + n] += acc;
}

// ---------------- final LN (last row only) + head --------------------------
__global__ __launch_bounds__(256) void ln_head_kernel(
    const float* __restrict__ h, const float* __restrict__ lng,
    const float* __restrict__ lnb, const float* __restrict__ hw,
    const float* __restrict__ hb, float* __restrict__ out)
{
    int b = blockIdx.x, tid = threadIdx.x;
    __shared__ float sh[DM];
    __shared__ float r1[4], r2[4];
    float v = h[((size_t)b * LL + (LL - 1)) * DM + tid];
    float s = v;
    #pragma unroll
    for (int o = 32; o >= 1; o >>= 1) s += __shfl_down(s, o);
    if ((tid & 63) == 0) r1[tid >> 6] = s;
    __syncthreads();
    float mu = (r1[0] + r1[1] + r1[2] + r1[3]) * (1.f / 256.f);
    float dv = v - mu;
    float q = dv * dv;
    #pragma unroll
    for (int o = 32; o >= 1; o >>= 1) q += __shfl_down(q, o);
    if ((tid & 63) == 0) r2[tid >> 6] = q;
    __syncthreads();
    float var = (r2[0] + r2[1] + r2[2] + r2[3]) * (1.f / 256.f);
    sh[tid] = dv * rsqrtf(var + LN_EPS) * lng[tid] + lnb[tid];
    __syncthreads();
    if (tid < NOUTK) {
        const float* wr = hw + (size_t)tid * DM;
        float acc = hb[tid];
        for (int d2 = 0; d2 < DM; d2 += 4) {
            float4 wv = *(const float4*)(wr + d2);
            acc = fmaf(sh[d2+0], wv.x, acc);
            acc = fmaf(sh[d2+1], wv.y, acc);
            acc = fmaf(sh[d2+2], wv.z, acc);
            acc = fmaf(sh[d2+3], wv.w, acc);
        }
        out[b * NOUTK + tid] = acc;
    }
}

extern "C" void kernel_launch(void* const* d_in, const int* in_sizes, int n_in,
                              void* d_out, int out_size, void* d_ws, size_t ws_size,
                              hipStream_t stream)
{
    const float* x    = (const float*)d_in[0];
    const float* encw = (const float*)d_in[1];
    const float* encb = (const float*)d_in[2];
    const float* inw  = (const float*)d_in[3];
    const float* cw   = (const float*)d_in[4];
    const float* cb   = (const float*)d_in[5];
    const float* xpw  = (const float*)d_in[6];
    const float* dtw  = (const float*)d_in[7];
    const float* dtb  = (const float*)d_in[8];
    const float* alog = (const float*)d_in[9];
    const float* Dp   = (const float*)d_in[10];
    const float* opw  = (const float*)d_in[11];
    const float* lng  = (const float*)d_in[12];
    const float* lnb  = (const float*)d_in[13];
    const float* hw   = (const float*)d_in[14];
    const float* hb   = (const float*)d_in[15];
    float* out = (float*)d_out;

    float* ws   = (float*)d_ws;
    float* h    = ws;                               // BL*256 f32
    float* bc   = h   + (size_t)BL * DM;            // BL*32 f32 (B|C)
    float* cA   = bc  + (size_t)BL * 32;            // B*DI*NC*16 f32
    float* cH   = cA  + (size_t)BB * DI * NC * DS;
    ushort* h_bf    = (ushort*)(cH + (size_t)BB * DI * NC * DS);
    ushort* xz_bf   = h_bf  + (size_t)BL * DM;      // BL*1024
    ushort* xi_bf   = xz_bf + (size_t)BL * 1024;    // BL*512
    ushort* dt_bf   = xi_bf + (size_t)BL * DI;      // BL*512 (softplus'd dt)
    ushort* inw_bf  = dt_bf + (size_t)BL * DI;      // 2*1024*256
    ushort* opw_bf  = inw_bf + 2 * 1024 * DM;       // 2*256*512
    ushort* comb_bf = opw_bf + 2 * DM * DI;         // 2*640*512

    dim3 blk(256, 1, 1);

    cast_bf16_kernel<<<dim3((2*1024*DM)/256), blk, 0, stream>>>(inw, inw_bf, 2*1024*DM);
    cast_bf16_kernel<<<dim3((2*DM*DI)/256), blk, 0, stream>>>(opw, opw_bf, 2*DM*DI);
    build_comb_kernel<<<dim3((2*640*512)/256), blk, 0, stream>>>(xpw, dtw, comb_bf);

    enc_kernel<<<dim3(BL/4), blk, 0, stream>>>(x, encw, encb, h, h_bf);

    for (int l = 0; l < 2; ++l) {
        // in_proj -> xz_bf (bf16 only)
        mfma_gemm<0,false,false,true><<<dim3(1024/128, BL/128), blk, 0, stream>>>(
            h_bf, DM, inw_bf + (size_t)l * 1024 * DM, nullptr,
            nullptr, 0, xz_bf, 1024, DM);
        // conv + silu -> xi_bf
        conv_silu_kernel<<<dim3(BL * 128 / 256), blk, 0, stream>>>(
            xz_bf, cw + l * DI * 4, cb + l * DI, xi_bf);
        // combined xproj+dtproj: dt_bf = bf16(softplus(xi@Wdt^T + dtb)),
        // bc = f32 [B|C]
        mfma_gemm<1,false,false,false><<<dim3(LDB/128, BL/128), blk, 0, stream>>>(
            xi_bf, DI, comb_bf + (size_t)l * LDB * DI, dtb + l * DI,
            bc, 32, dt_bf, 512, DI);
        // scan
        scan_phase1<<<dim3(NC, BB, 2), blk, 0, stream>>>(
            xi_bf, dt_bf, bc, alog + (size_t)l * DI * 16, cA, cH);
        scan_phase2<<<dim3(BB * DI * DS / 256), blk, 0, stream>>>(cA, cH);
        if (l == 0) {
            scan_phase3<<<dim3(NC, BB, 2), blk, 0, stream>>>(
                xz_bf, xi_bf, dt_bf, bc, alog + (size_t)l * DI * 16,
                Dp + l * DI, cH, 0);
            mfma_gemm<0,true,true,true><<<dim3(DM/128, BL/128), blk, 0, stream>>>(
                xi_bf, DI, opw_bf + (size_t)l * DM * DI, nullptr,
                h, DM, h_bf, DM, DI);
        } else {
            scan_phase3<<<dim3(1, BB, 2), blk, 0, stream>>>(
                xz_bf, xi_bf, dt_bf, bc, alog + (size_t)l * DI * 16,
                Dp + l * DI, cH, NC - 1);
            out_proj_last_kernel<<<dim3(BB), blk, 0, stream>>>(
                xi_bf, opw + (size_t)l * DM * DI, h);
        }
    }

    ln_head_kernel<<<dim3(BB), blk, 0, stream>>>(h, lng, lnb, hw, hb, out);
}

// Round 2
// 343.977 us; speedup vs baseline: 1.1944x; 1.0905x over previous
//
#include <hip/hip_runtime.h>
#include <hip/hip_bf16.h>
#include <math.h>

#define BB 4
#define LL 4096
#define DM 256
#define DI 512
#define DS 16
#define NOUTK 128
#define LN_EPS 1e-5f
#define NC 128
#define CLEN (LL/NC)
#define BL (BB*LL)
#define LDB 640

typedef __attribute__((ext_vector_type(8))) short short8;
typedef __attribute__((ext_vector_type(4))) float f32x4;

__device__ __forceinline__ ushort f2bf(float f) {
    union { float f; unsigned u; } v; v.f = f;
    unsigned r = (v.u + 0x7FFF + ((v.u >> 16) & 1)) >> 16;
    return (ushort)r;
}
__device__ __forceinline__ float bf2f(ushort u) {
    union { unsigned u; float f; } v; v.u = ((unsigned)u) << 16;
    return v.f;
}

// ---------------- weight prep ----------------------------------------------
__global__ __launch_bounds__(256) void cast_bf16_kernel(
    const float* __restrict__ src, ushort* __restrict__ dst, int n)
{
    int i = blockIdx.x * 256 + threadIdx.x;
    if (i < n) dst[i] = f2bf(src[i]);
}

// combined xproj weight: rows [0,512) = dtw @ xpw[:16]  (fused dtproj)
//                        rows [512,544) = xpw rows 16..47 (B, C)
//                        rows [544,640) = 0
__global__ __launch_bounds__(256) void build_comb_kernel(
    const float* __restrict__ xpw, const float* __restrict__ dtw,
    ushort* __restrict__ dst)
{
    int i = blockIdx.x * 256 + threadIdx.x;      // over 2*640*512
    int l = i / (640 * 512);
    int rem = i - l * 640 * 512;
    int row = rem >> 9, k = rem & 511;
    const float* xp = xpw + l * 48 * 512;
    const float* dw = dtw + l * 512 * 16;
    float v;
    if (row < 512) {
        v = 0.f;
        #pragma unroll
        for (int r = 0; r < 16; ++r)
            v = fmaf(dw[row * 16 + r], xp[r * 512 + k], v);
    } else if (row < 544) {
        v = xp[(row - 512 + 16) * 512 + k];
    } else v = 0.f;
    dst[i] = f2bf(v);
}

// ---------------- encoder --------------------------------------------------
__global__ __launch_bounds__(256) void enc_kernel(
    const float* __restrict__ x, const float* __restrict__ w,
    const float* __restrict__ b, float* __restrict__ h,
    ushort* __restrict__ hbf)
{
    __shared__ float sw[256 * 33];
    __shared__ float sx[4][32];
    int tid = threadIdx.x;
    for (int i = tid; i < 256 * 8; i += 256) {
        float4 v = ((const float4*)w)[i];
        int r = i >> 3, c = (i & 7) * 4;
        sw[r * 33 + c + 0] = v.x; sw[r * 33 + c + 1] = v.y;
        sw[r * 33 + c + 2] = v.z; sw[r * 33 + c + 3] = v.w;
    }
    int row0 = blockIdx.x * 4;
    if (tid < 32) {
        for (int rr = 0; rr < 4; ++rr)
            sx[rr][tid] = x[(size_t)(row0 + rr) * 32 + tid];
    }
    __syncthreads();
    float bb = b[tid];
    #pragma unroll
    for (int rr = 0; rr < 4; ++rr) {
        float acc = bb;
        #pragma unroll
        for (int k = 0; k < 32; ++k)
            acc = fmaf(sx[rr][k], sw[tid * 33 + k], acc);
        size_t o = (size_t)(row0 + rr) * DM + tid;
        h[o] = acc;
        hbf[o] = f2bf(acc);
    }
}

// ---------------- bf16 MFMA GEMM: C = epi(A @ W^T) -------------------------
// Tile 64(M) x 128(N), 4 waves of 32x64, single-buffered 24 KB LDS
// (m97-style 2-barrier k-loop; latency hidden by 5-6 co-resident blocks).
// EPI: 0 none; 1 combined-xproj:
//        cols<512:   dt_bf[row*ldcbf+col]  = bf16(softplus(v + bias[col]))
//        512<=c<544: bc  [row*ldc + c-512] = v   (f32 B/C block)
template<int EPI, bool F32OUT, bool RESID, bool BF16OUT>
__global__ __launch_bounds__(256, 4) void mfma_gemm(
    const ushort* __restrict__ A, int lda,
    const ushort* __restrict__ W,
    const float* __restrict__ bias,
    float* __restrict__ C, int ldc,
    ushort* __restrict__ Cbf, int ldcbf,
    int K)
{
    __shared__ ushort As[64 * 64];
    __shared__ ushort Ws[128 * 64];
    const int tid = threadIdx.x;

    // XCD-aware bijective swizzle (nwg % 8 == 0 for all our launches)
    int nwg = gridDim.x * gridDim.y;
    int wlin = blockIdx.y * gridDim.x + blockIdx.x;
    int gx = blockIdx.x, gy = blockIdx.y;
    if ((nwg & 7) == 0) {
        int q = nwg >> 3;
        int s = (wlin & 7) * q + (wlin >> 3);
        gx = s % gridDim.x;
        gy = s / gridDim.x;
    }
    const int bm = gy * 64;
    const int bn = gx * 128;
    const int wid = tid >> 6, lane = tid & 63;
    const int wrow = (wid >> 1) * 32, wcol = (wid & 1) * 64;
    const int sr = tid >> 3;
    const int sc = tid & 7;

    f32x4 acc[2][4];
    #pragma unroll
    for (int mi = 0; mi < 2; ++mi)
        #pragma unroll
        for (int ni = 0; ni < 4; ++ni)
            acc[mi][ni] = (f32x4){0.f, 0.f, 0.f, 0.f};

    const int nk = K >> 6;          // 4 (K=256) or 8 (K=512)
    for (int t = 0; t < nk; ++t) {
        const int k0 = t << 6;
        #pragma unroll
        for (int it = 0; it < 2; ++it) {
            int r = it * 32 + sr;
            int csrc = sc ^ (r & 7);
            __builtin_amdgcn_global_load_lds(
                (const __attribute__((address_space(1))) unsigned int*)
                    (A + (size_t)(bm + r) * lda + k0 + csrc * 8),
                (__attribute__((address_space(3))) unsigned int*)
                    (As + r * 64 + sc * 8), 16, 0, 0);
        }
        #pragma unroll
        for (int it = 0; it < 4; ++it) {
            int r = it * 32 + sr;
            int csrc = sc ^ (r & 7);
            __builtin_amdgcn_global_load_lds(
                (const __attribute__((address_space(1))) unsigned int*)
                    (W + (size_t)(bn + r) * K + k0 + csrc * 8),
                (__attribute__((address_space(3))) unsigned int*)
                    (Ws + r * 64 + sc * 8), 16, 0, 0);
        }
        __syncthreads();
        #pragma unroll
        for (int kk = 0; kk < 2; ++kk) {
            short8 af[2], bfr[4];
            #pragma unroll
            for (int mi = 0; mi < 2; ++mi) {
                int r = wrow + mi * 16 + (lane & 15);
                int c = (lane >> 4) + kk * 4;
                af[mi] = *(const short8*)(As + r * 64 + ((c ^ (r & 7)) << 3));
            }
            #pragma unroll
            for (int ni = 0; ni < 4; ++ni) {
                int r = wcol + ni * 16 + (lane & 15);
                int c = (lane >> 4) + kk * 4;
                bfr[ni] = *(const short8*)(Ws + r * 64 + ((c ^ (r & 7)) << 3));
            }
            #pragma unroll
            for (int mi = 0; mi < 2; ++mi)
                #pragma unroll
                for (int ni = 0; ni < 4; ++ni)
                    acc[mi][ni] = __builtin_amdgcn_mfma_f32_16x16x32_bf16(
                        af[mi], bfr[ni], acc[mi][ni], 0, 0, 0);
        }
        __syncthreads();
    }

    #pragma unroll
    for (int mi = 0; mi < 2; ++mi)
        #pragma unroll
        for (int ni = 0; ni < 4; ++ni) {
            int col = bn + wcol + ni * 16 + (lane & 15);
            #pragma unroll
            for (int r = 0; r < 4; ++r) {
                int row = bm + wrow + mi * 16 + (lane >> 4) * 4 + r;
                float v = acc[mi][ni][r];
                if (EPI == 1) {
                    if (col < 512) {
                        float u = v + bias[col];
                        float sp = fmaxf(u, 0.f) + __logf(1.f + __expf(-fabsf(u)));
                        Cbf[(size_t)row * ldcbf + col] = f2bf(sp);
                    } else if (col < 544) {
                        C[(size_t)row * ldc + (col - 512)] = v;
                    }
                } else {
                    if (F32OUT) {
                        float* cp = C + (size_t)row * ldc + col;
                        float vv = v;
                        if (RESID) vv += *cp;
                        *cp = vv;
                        if (BF16OUT) Cbf[(size_t)row * ldcbf + col] = f2bf(vv);
                    } else if (BF16OUT) {
                        Cbf[(size_t)row * ldcbf + col] = f2bf(v);
                    }
                }
            }
        }
}

// ---------------- causal conv (width 4) + bias + silu, bf16 in/out ---------
__global__ __launch_bounds__(256) void conv_silu_kernel(
    const ushort* __restrict__ xz, const float* __restrict__ cw,
    const float* __restrict__ cb, ushort* __restrict__ xi)
{
    int idx = blockIdx.x * 256 + threadIdx.x;   // over BL*128
    int d4 = (idx & 127) * 4;
    int bt = idx >> 7;
    int t = bt & (LL - 1);
    const ushort* base = xz + (size_t)bt * 1024 + d4;
    float acc[4];
    float4 w[4];
    #pragma unroll
    for (int j = 0; j < 4; ++j) {
        acc[j] = cb[d4 + j];
        w[j] = *(const float4*)(cw + (d4 + j) * 4);
    }
    #pragma unroll
    for (int k = 0; k < 4; ++k) {
        int back = 3 - k;
        if (t >= back) {
            ushort4 v = *(const ushort4*)(base - back * 1024);
            float wk0 = (k==0)?w[0].x:(k==1)?w[0].y:(k==2)?w[0].z:w[0].w;
            float wk1 = (k==0)?w[1].x:(k==1)?w[1].y:(k==2)?w[1].z:w[1].w;
            float wk2 = (k==0)?w[2].x:(k==1)?w[2].y:(k==2)?w[2].z:w[2].w;
            float wk3 = (k==0)?w[3].x:(k==1)?w[3].y:(k==2)?w[3].z:w[3].w;
            acc[0] = fmaf(bf2f(v.x), wk0, acc[0]);
            acc[1] = fmaf(bf2f(v.y), wk1, acc[1]);
            acc[2] = fmaf(bf2f(v.z), wk2, acc[2]);
            acc[3] = fmaf(bf2f(v.w), wk3, acc[3]);
        }
    }
    ushort4 o;
    float s0 = acc[0] / (1.f + __expf(-acc[0]));
    float s1 = acc[1] / (1.f + __expf(-acc[1]));
    float s2 = acc[2] / (1.f + __expf(-acc[2]));
    float s3 = acc[3] / (1.f + __expf(-acc[3]));
    o.x = f2bf(s0); o.y = f2bf(s1); o.z = f2bf(s2); o.w = f2bf(s3);
    *(ushort4*)(xi + (size_t)bt * 512 + d4) = o;
}

// ---------------- chunked selective scan -----------------------------------
// dt (softplus applied) is bf16 at dtb[row*512 + d]; B/C are f32 at
// bc[row*32 + {0..15 | 16..31}].
__global__ __launch_bounds__(256) void scan_phase1(
    const ushort* __restrict__ xi, const ushort* __restrict__ dtb,
    const float* __restrict__ bc,
    const float* __restrict__ alog,
    float* __restrict__ cA, float* __restrict__ cH)
{
    int d = blockIdx.z * 256 + threadIdx.x;
    int b = blockIdx.y, c = blockIdx.x;
    float Av[16];
    bool fast = true;
    #pragma unroll
    for (int s = 0; s < 16; ++s) {
        Av[s] = -__expf(alog[d * 16 + s]);
        fast = fast && (fabsf(Av[s] + (float)(s + 1)) < 1e-3f * (s + 1));
    }
    float h[16], P[16];
    #pragma unroll
    for (int s = 0; s < 16; ++s) { h[s] = 0.f; P[s] = 1.f; }
    int t0 = c * CLEN;
    if (fast) {
        float Pe = 1.f;
        for (int t = t0; t < t0 + CLEN; ++t) {
            size_t row = (size_t)b * LL + t;
            float dt = bf2f(dtb[row * 512 + d]);
            float x = bf2f(xi[row * 512 + d]);
            float dtx = dt * x;
            const float* bp = bc + row * 32;
            float e1 = __expf(-dt);
            float e2=e1*e1, e3=e2*e1, e4=e2*e2, e5=e3*e2, e6=e3*e3, e7=e4*e3, e8=e4*e4;
            float e9=e5*e4, e10=e5*e5, e11=e6*e5, e12=e6*e6, e13=e7*e6, e14=e7*e7, e15=e8*e7, e16=e8*e8;
            float pw[16] = {e1,e2,e3,e4,e5,e6,e7,e8,e9,e10,e11,e12,e13,e14,e15,e16};
            #pragma unroll
            for (int s = 0; s < 16; ++s)
                h[s] = fmaf(pw[s], h[s], dtx * bp[s]);
            Pe *= e1;
        }
        float p1=Pe, p2=p1*p1, p3=p2*p1, p4=p2*p2, p5=p3*p2, p6=p3*p3, p7=p4*p3, p8=p4*p4;
        float p9=p5*p4, p10=p5*p5, p11=p6*p5, p12=p6*p6, p13=p7*p6, p14=p7*p7, p15=p8*p7, p16=p8*p8;
        float pp[16] = {p1,p2,p3,p4,p5,p6,p7,p8,p9,p10,p11,p12,p13,p14,p15,p16};
        #pragma unroll
        for (int s = 0; s < 16; ++s) P[s] = pp[s];
    } else {
        for (int t = t0; t < t0 + CLEN; ++t) {
            size_t row = (size_t)b * LL + t;
            float dt = bf2f(dtb[row * 512 + d]);
            float x = bf2f(xi[row * 512 + d]);
            float dtx = dt * x;
            const float* bp = bc + row * 32;
            #pragma unroll
            for (int s = 0; s < 16; ++s) {
                float dA = __expf(dt * Av[s]);
                h[s] = fmaf(dA, h[s], dtx * bp[s]);
                P[s] *= dA;
            }
        }
    }
    size_t base = (((size_t)b * DI + d) * NC + c) * 16;
    #pragma unroll
    for (int q = 0; q < 4; ++q) {
        *(float4*)(cA + base + q*4) = *(float4*)&P[q*4];
        *(float4*)(cH + base + q*4) = *(float4*)&h[q*4];
    }
}

__global__ __launch_bounds__(256) void scan_phase2(
    const float* __restrict__ cA, float* __restrict__ cH)
{
    int idx = blockIdx.x * 256 + threadIdx.x;  // (b*DI+d)*16 + s
    int s = idx & 15;
    int bd = idx >> 4;
    size_t base = (size_t)bd * NC * 16 + s;
    float init = 0.f;
    for (int c = 0; c < NC; ++c) {
        size_t o = base + (size_t)c * 16;
        float a = cA[o], hh = cH[o];
        cH[o] = init;
        init = fmaf(a, init, hh);
    }
}

__global__ __launch_bounds__(256) void scan_phase3(
    const ushort* __restrict__ xz,   // bf16, ld 1024; res at cols 512..1023
    ushort* __restrict__ xi,
    const ushort* __restrict__ dtb,
    const float* __restrict__ bc,
    const float* __restrict__ alog,
    const float* __restrict__ Dp,
    const float* __restrict__ cH,
    int c0)
{
    int d = blockIdx.z * 256 + threadIdx.x;
    int b = blockIdx.y;
    int c = blockIdx.x + c0;
    float Av[16];
    bool fast = true;
    #pragma unroll
    for (int s = 0; s < 16; ++s) {
        Av[s] = -__expf(alog[d * 16 + s]);
        fast = fast && (fabsf(Av[s] + (float)(s + 1)) < 1e-3f * (s + 1));
    }
    float h[16];
    size_t cbase = (((size_t)b * DI + d) * NC + c) * 16;
    #pragma unroll
    for (int q = 0; q < 4; ++q)
        *(float4*)&h[q*4] = *(const float4*)(cH + cbase + q*4);
    float Dd = Dp[d];
    int t0 = c * CLEN;
    if (fast) {
        for (int t = t0; t < t0 + CLEN; ++t) {
            size_t row = (size_t)b * LL + t;
            float dt = bf2f(dtb[row * 512 + d]);
            float x = bf2f(xi[row * 512 + d]);
            float dtx = dt * x;
            const float* bp = bc + row * 32;
            const float* cp = bc + row * 32 + 16;
            float e1 = __expf(-dt);
            float e2=e1*e1, e3=e2*e1, e4=e2*e2, e5=e3*e2, e6=e3*e3, e7=e4*e3, e8=e4*e4;
            float e9=e5*e4, e10=e5*e5, e11=e6*e5, e12=e6*e6, e13=e7*e6, e14=e7*e7, e15=e8*e7, e16=e8*e8;
            float pw[16] = {e1,e2,e3,e4,e5,e6,e7,e8,e9,e10,e11,e12,e13,e14,e15,e16};
            float y = 0.f;
            #pragma unroll
            for (int s = 0; s < 16; ++s) {
                h[s] = fmaf(pw[s], h[s], dtx * bp[s]);
                y = fmaf(h[s], cp[s], y);
            }
            float res = bf2f(xz[row * 1024 + 512 + d]);
            float g = (y + x * Dd) * (res / (1.f + __expf(-res)));
            xi[row * 512 + d] = f2bf(g);
        }
    } else {
        for (int t = t0; t < t0 + CLEN; ++t) {
            size_t row = (size_t)b * LL + t;
            float dt = bf2f(dtb[row * 512 + d]);
            float x = bf2f(xi[row * 512 + d]);
            float dtx = dt * x;
            const float* bp = bc + row * 32;
            const float* cp = bc + row * 32 + 16;
            float y = 0.f;
            #pragma unroll
            for (int s = 0; s < 16; ++s) {
                float dA = __expf(dt * Av[s]);
                h[s] = fmaf(dA, h[s], dtx * bp[s]);
                y = fmaf(h[s], cp[s], y);
            }
            float res = bf2f(xz[row * 1024 + 512 + d]);
            float g = (y + x * Dd) * (res / (1.f + __expf(-res)));
            xi[row * 512 + d] = f2bf(g);
        }
    }
}

// ---------------- last-row out_proj (layer 2) ------------------------------
__global__ __launch_bounds__(256) void out_proj_last_kernel(
    const ushort* __restrict__ xi, const float* __restrict__ W,
    float* __restrict__ h)
{
    int b = blockIdx.x, n = threadIdx.x;
    __shared__ float sy[DI];
    const ushort* yrow = xi + ((size_t)b * LL + (LL - 1)) * DI;
    for (int k = threadIdx.x; k < DI; k += 256) sy[k] = bf2f(yrow[k]);
    __syncthreads();
    const float* wr = W + (size_t)n * DI;
    float acc = 0.f;
    for (int k = 0; k < DI; k += 4) {
        float4 wv = *(const float4*)(wr + k);
        acc = fmaf(sy[k+0], wv.x, acc);
        acc = fmaf(sy[k+1], wv.y, acc);
        acc = fmaf(sy[k+2], wv.z, acc);
        acc = fmaf(sy[k+3], wv.w, acc);
    }
    h[((size_t)b * LL + (LL - 1)) * DM + n] += acc;
}

// ---------------- final LN (last row only) + head --------------------------
__global__ __launch_bounds__(256) void ln_head_kernel(
    const float* __restrict__ h, const float* __restrict__ lng,
    const float* __restrict__ lnb, const float* __restrict__ hw,
    const float* __restrict__ hb, float* __restrict__ out)
{
    int b = blockIdx.x, tid = threadIdx.x;
    __shared__ float sh[DM];
    __shared__ float r1[4], r2[4];
    float v = h[((size_t)b * LL + (LL - 1)) * DM + tid];
    float s = v;
    #pragma unroll
    for (int o = 32; o >= 1; o >>= 1) s += __shfl_down(s, o);
    if ((tid & 63) == 0) r1[tid >> 6] = s;
    __syncthreads();
    float mu = (r1[0] + r1[1] + r1[2] + r1[3]) * (1.f / 256.f);
    float dv = v - mu;
    float q = dv * dv;
    #pragma unroll
    for (int o = 32; o >= 1; o >>= 1) q += __shfl_down(q, o);
    if ((tid & 63) == 0) r2[tid >> 6] = q;
    __syncthreads();
    float var = (r2[0] + r2[1] + r2[2] + r2[3]) * (1.f / 256.f);
    sh[tid] = dv * rsqrtf(var + LN_EPS) * lng[tid] + lnb[tid];
    __syncthreads();
    if (tid < NOUTK) {
        const float* wr = hw + (size_t)tid * DM;
        float acc = hb[tid];
        for (int d2 = 0; d2 < DM; d2 += 4) {
            float4 wv = *(const float4*)(wr + d2);
            acc = fmaf(sh[d2+0], wv.x, acc);
            acc = fmaf(sh[d2+1], wv.y, acc);
            acc = fmaf(sh[d2+2], wv.z, acc);
            acc = fmaf(sh[d2+3], wv.w, acc);
        }
        out[b * NOUTK + tid] = acc;
    }
}

extern "C" void kernel_launch(void* const* d_in, const int* in_sizes, int n_in,
                              void* d_out, int out_size, void* d_ws, size_t ws_size,
                              hipStream_t stream)
{
    const float* x    = (const float*)d_in[0];
    const float* encw = (const float*)d_in[1];
    const float* encb = (const float*)d_in[2];
    const float* inw  = (const float*)d_in[3];
    const float* cw   = (const float*)d_in[4];
    const float* cb   = (const float*)d_in[5];
    const float* xpw  = (const float*)d_in[6];
    const float* dtw  = (const float*)d_in[7];
    const float* dtb  = (const float*)d_in[8];
    const float* alog = (const float*)d_in[9];
    const float* Dp   = (const float*)d_in[10];
    const float* opw  = (const float*)d_in[11];
    const float* lng  = (const float*)d_in[12];
    const float* lnb  = (const float*)d_in[13];
    const float* hw   = (const float*)d_in[14];
    const float* hb   = (const float*)d_in[15];
    float* out = (float*)d_out;

    float* ws   = (float*)d_ws;
    float* h    = ws;                               // BL*256 f32
    float* bc   = h   + (size_t)BL * DM;            // BL*32 f32 (B|C)
    float* cA   = bc  + (size_t)BL * 32;            // B*DI*NC*16 f32
    float* cH   = cA  + (size_t)BB * DI * NC * DS;
    ushort* h_bf    = (ushort*)(cH + (size_t)BB * DI * NC * DS);
    ushort* xz_bf   = h_bf  + (size_t)BL * DM;      // BL*1024
    ushort* xi_bf   = xz_bf + (size_t)BL * 1024;    // BL*512
    ushort* dt_bf   = xi_bf + (size_t)BL * DI;      // BL*512 (softplus'd dt)
    ushort* inw_bf  = dt_bf + (size_t)BL * DI;      // 2*1024*256
    ushort* opw_bf  = inw_bf + 2 * 1024 * DM;       // 2*256*512
    ushort* comb_bf = opw_bf + 2 * DM * DI;         // 2*640*512

    dim3 blk(256, 1, 1);

    cast_bf16_kernel<<<dim3((2*1024*DM)/256), blk, 0, stream>>>(inw, inw_bf, 2*1024*DM);
    cast_bf16_kernel<<<dim3((2*DM*DI)/256), blk, 0, stream>>>(opw, opw_bf, 2*DM*DI);
    build_comb_kernel<<<dim3((2*640*512)/256), blk, 0, stream>>>(xpw, dtw, comb_bf);

    enc_kernel<<<dim3(BL/4), blk, 0, stream>>>(x, encw, encb, h, h_bf);

    for (int l = 0; l < 2; ++l) {
        // in_proj -> xz_bf (bf16 only)
        mfma_gemm<0,false,false,true><<<dim3(1024/128, BL/64), blk, 0, stream>>>(
            h_bf, DM, inw_bf + (size_t)l * 1024 * DM, nullptr,
            nullptr, 0, xz_bf, 1024, DM);
        // conv + silu -> xi_bf
        conv_silu_kernel<<<dim3(BL * 128 / 256), blk, 0, stream>>>(
            xz_bf, cw + l * DI * 4, cb + l * DI, xi_bf);
        // combined xproj+dtproj: dt_bf = bf16(softplus(xi@Wdt^T + dtb)),
        // bc = f32 [B|C]
        mfma_gemm<1,false,false,false><<<dim3(LDB/128, BL/64), blk, 0, stream>>>(
            xi_bf, DI, comb_bf + (size_t)l * LDB * DI, dtb + l * DI,
            bc, 32, dt_bf, 512, DI);
        // scan
        scan_phase1<<<dim3(NC, BB, 2), blk, 0, stream>>>(
            xi_bf, dt_bf, bc, alog + (size_t)l * DI * 16, cA, cH);
        scan_phase2<<<dim3(BB * DI * DS / 256), blk, 0, stream>>>(cA, cH);
        if (l == 0) {
            scan_phase3<<<dim3(NC, BB, 2), blk, 0, stream>>>(
                xz_bf, xi_bf, dt_bf, bc, alog + (size_t)l * DI * 16,
                Dp + l * DI, cH, 0);
            mfma_gemm<0,true,true,true><<<dim3(DM/128, BL/64), blk, 0, stream>>>(
                xi_bf, DI, opw_bf + (size_t)l * DM * DI, nullptr,
                h, DM, h_bf, DM, DI);
        } else {
            scan_phase3<<<dim3(1, BB, 2), blk, 0, stream>>>(
                xz_bf, xi_bf, dt_bf, bc, alog + (size_t)l * DI * 16,
                Dp + l * DI, cH, NC - 1);
            out_proj_last_kernel<<<dim3(BB), blk, 0, stream>>>(
                xi_bf, opw + (size_t)l * DM * DI, h);
        }
    }

    ln_head_kernel<<<dim3(BB), blk, 0, stream>>>(h, lng, lnb, hw, hb, out);
}